// Round 7
// baseline (712.166 us; speedup 1.0000x reference)
//
#include <hip/hip_runtime.h>
#include <cstdint>
#include <cstddef>

#define N_TOK 8192
#define DM 1024
#define DFF 4096
#define NE 8
#define PAD 256
#define CAP (N_TOK * 2 + NE * PAD)  // 18432
#define TMG (CAP / 256)             // 72 global row-tiles

typedef __attribute__((ext_vector_type(8))) short bf16x8;
typedef __attribute__((ext_vector_type(4))) float f32x4;

__device__ __forceinline__ unsigned short f2bf(float f) {
  union { float f; unsigned u; } v; v.f = f;
  unsigned r = v.u + 0x7FFFu + ((v.u >> 16) & 1u);
  return (unsigned short)(r >> 16);
}

__device__ __forceinline__ void async16(unsigned short* l, const unsigned short* g) {
  __builtin_amdgcn_global_load_lds(
      (const __attribute__((address_space(1))) unsigned int*)g,
      (__attribute__((address_space(3))) unsigned int*)l, 16, 0, 0);
}

// ---------------- init ----------------
__global__ void init_kernel(unsigned* counts, float* Psum) {
  int i = threadIdx.x;
  if (i < NE) { counts[i] = 0u; Psum[i] = 0.f; }
}

// ---------------- transpose + fp32->bf16 convert ----------------
__global__ __launch_bounds__(256) void transpose_cvt(
    const float* __restrict__ in, unsigned short* __restrict__ out, int R, int C) {
  __shared__ float tile[64][65];
  const float* I = in + (size_t)blockIdx.z * R * C;
  unsigned short* O = out + (size_t)blockIdx.z * R * C;
  const int r0 = blockIdx.y * 64, c0 = blockIdx.x * 64;
  const int c = threadIdx.x & 63, r4 = threadIdx.x >> 6;
#pragma unroll
  for (int i = 0; i < 16; ++i) {
    int r = r4 * 16 + i;
    tile[r][c] = I[(size_t)(r0 + r) * C + c0 + c];
  }
  __syncthreads();
#pragma unroll
  for (int i = 0; i < 16; ++i) {
    int r = r4 * 16 + i;
    O[(size_t)(c0 + r) * R + r0 + c] = f2bf(tile[c][r]);
  }
}

// ---------------- router ----------------
__global__ __launch_bounds__(256) void router_kernel(
    const float* __restrict__ x, const float* __restrict__ Wr,
    unsigned* __restrict__ counts, float* __restrict__ Psum,
    int* __restrict__ tok_e, float* __restrict__ tok_g, int* __restrict__ tok_ls) {
  __shared__ float ps[NE];
  const int tid = threadIdx.x;
  if (tid < NE) ps[tid] = 0.f;
  __syncthreads();
  const int lane = tid & 63, wid = tid >> 6;
  for (int u = 0; u < 4; ++u) {
    const int t = blockIdx.x * 16 + wid * 4 + u;
    float a[NE];
#pragma unroll
    for (int e = 0; e < NE; ++e) a[e] = 0.f;
#pragma unroll
    for (int i = 0; i < 16; ++i) {
      const int d = i * 64 + lane;
      const float xv = x[(size_t)t * DM + d];
      const float* wr = &Wr[(size_t)d * NE];
#pragma unroll
      for (int e = 0; e < NE; ++e) a[e] = fmaf(xv, wr[e], a[e]);
    }
#pragma unroll
    for (int e = 0; e < NE; ++e)
      for (int s = 32; s > 0; s >>= 1) a[e] += __shfl_xor(a[e], s);
    float mx = a[0];
#pragma unroll
    for (int e = 1; e < NE; ++e) mx = fmaxf(mx, a[e]);
    float p[NE], s = 0.f;
#pragma unroll
    for (int e = 0; e < NE; ++e) { p[e] = expf(a[e] - mx); s += p[e]; }
    float q[NE];
#pragma unroll
    for (int e = 0; e < NE; ++e) q[e] = p[e] / s;
    int i0 = 0; float b0 = q[0];
#pragma unroll
    for (int e = 1; e < NE; ++e) if (q[e] > b0) { b0 = q[e]; i0 = e; }
    int i1 = -1; float b1v = -1.f;
#pragma unroll
    for (int e = 0; e < NE; ++e) if (e != i0 && q[e] > b1v) { b1v = q[e]; i1 = e; }
    const float gs = q[i0] + q[i1];
    const float g0 = q[i0] / gs, g1 = q[i1] / gs;
    if (lane == 0) {
#pragma unroll
      for (int e = 0; e < NE; ++e) atomicAdd(&ps[e], q[e]);
      const int ls0 = (int)atomicAdd(&counts[i0], 1u);
      const int ls1 = (int)atomicAdd(&counts[i1], 1u);
      tok_e[2 * t] = i0; tok_e[2 * t + 1] = i1;
      tok_g[2 * t] = g0; tok_g[2 * t + 1] = g1;
      tok_ls[2 * t] = ls0; tok_ls[2 * t + 1] = ls1;
    }
  }
  __syncthreads();
  if (tid < NE) atomicAdd(&Psum[tid], ps[tid]);
}

// ---------------- offsets (256-padded prefix) + total + aux loss ----------------
__global__ void offsets_kernel(const unsigned* __restrict__ counts,
                               const float* __restrict__ Psum,
                               int* __restrict__ offs, float* __restrict__ aux_out) {
  if (threadIdx.x == 0 && blockIdx.x == 0) {
    int o = 0; float aux = 0.f;
    for (int e = 0; e < NE; ++e) {
      offs[e] = o;
      o += (int)((counts[e] + (PAD - 1u)) / PAD) * PAD;
      aux += ((float)counts[e] / (float)N_TOK) * (Psum[e] / (float)N_TOK);
    }
    offs[NE] = o;  // total padded rows
    aux_out[0] = 0.01f * (float)NE * aux;
  }
}

// ---------------- gather ----------------
__global__ __launch_bounds__(256) void gather_kernel(
    const float* __restrict__ x, const int* __restrict__ tok_e,
    const int* __restrict__ tok_ls, const int* __restrict__ offs,
    int* __restrict__ tok_slot, unsigned short* __restrict__ Xg) {
  const int t = blockIdx.x;
  __shared__ int ss[2];
  if (threadIdx.x < 2) {
    const int k = threadIdx.x;
    const int e = tok_e[2 * t + k];
    const int sl = offs[e] + tok_ls[2 * t + k];
    ss[k] = sl;
    tok_slot[2 * t + k] = sl;
  }
  __syncthreads();
  const int i = threadIdx.x;
  const float4 v = ((const float4*)x)[(size_t)t * 256 + i];
  ushort4 h;
  h.x = f2bf(v.x); h.y = f2bf(v.y); h.z = f2bf(v.z); h.w = f2bf(v.w);
  ((ushort4*)Xg)[(size_t)ss[0] * 256 + i] = h;
  ((ushort4*)Xg)[(size_t)ss[1] * 256 + i] = h;
}

// ---------------- 8-phase 256x256 GEMM, m201-faithful two-barrier phases ------
// C(rows x Nn) = A(rows x K)*Bt(Nn x K)^T + bias. 512 thr = 8 waves (2M x 4N).
// LDS 128KB: per matrix 4 static regions [db(2)][half(2)] of 128 rows x 64 cols
// bf16; 16B chunks XOR-swizzled by (row&7) both sides (conflict-free, R6-verified).
// Region/stage/vmcnt LEDGER IDENTICAL to R6 (absmax-proven). Only sync structure
// changed to the m201 template (m196 A/B-verified winner):
//   phase = { ds_reads ; stage ; [lgkmcnt(8) if 12 reads] ; s_barrier ;
//             lgkmcnt(0) ; setprio(1) ; 16 MFMA ; setprio(0) ; s_barrier }
// NO sched_barrier(0) pins (m141 anti-pattern). Balanced reads 12/4/8/0 per
// K-tile. vmcnt(4) once per K-tile (P3/P7 mem window) = counted, never 0.
template <int SPLIT, bool GELU, typename CT>
__global__ __launch_bounds__(512, 2) void gemm8(
    const unsigned short* __restrict__ Ag, const unsigned short* __restrict__ Bt,
    const float* __restrict__ bias, CT* __restrict__ Cout,
    const int* __restrict__ offs, const int K, const int Nn,
    const size_t c_split_stride) {
  const int gr = blockIdx.y;
  const int grow = gr * 256;
  if (grow >= offs[NE]) return;
  int e = 0;
#pragma unroll
  for (int k = 1; k < NE; ++k) if (offs[k] <= grow) e = k;
  const int ks = (SPLIT == 1) ? 0 : (int)blockIdx.z;
  const int tn = blockIdx.x;
  const int row0 = grow;
  const int kext = K / SPLIT;
  const int nt = kext >> 6;  // K-tiles of 64

  const unsigned short* A = Ag + (size_t)row0 * K + (size_t)ks * kext;
  const unsigned short* B = Bt + ((size_t)e * Nn + (size_t)tn * 256) * K + (size_t)ks * kext;
  const float* bp = (ks == 0) ? bias : nullptr;
  CT* Cw = Cout + (size_t)ks * c_split_stride;

  extern __shared__ unsigned short lds[];
  unsigned short* LA = lds;            // 4 regions x 8192 shorts
  unsigned short* LB = lds + 32768;
  const int REG = 8192;

  const int tid = threadIdx.x;
  const int lane = tid & 63;
  const int wid = tid >> 6;
  const int wm = wid >> 2;    // 0..1 -> A half
  const int wn = wid & 3;     // 0..3; B half = wn>>1
  const int wnh = wn >> 1;
  const int arow = lane & 15;
  const int kc = lane >> 4;   // 0..3

  // LDS read swizzle constants: chunk (s*4+kc) ^ (row&7); row&7 == arow&7.
  const int sc0 = ((kc ^ (arow & 7)) << 3);
  const int sc1 = (((4 + kc) ^ (arow & 7)) << 3);
  const int rA0 = (0 * 2 + wm) * REG, rA1 = (1 * 2 + wm) * REG;
  const int rB0 = (0 * 2 + wnh) * REG, rB1 = (1 * 2 + wnh) * REG;
  const int aRow = arow * 64;                       // + mf*1024
  const int bRow = ((wn & 1) * 64 + arow) * 64;     // + nf*1024

  // stage addressing: thread t covers chunk (it*512 + t); r = it*64 + (t>>3);
  // src col-chunk = (t&7) ^ ((t>>3)&7) -> per-thread constant.
  const int r0t = (tid >> 3);
  const int sswz = ((tid & 7) ^ ((tid >> 3) & 7)) << 3;
  const unsigned short* sA = A + (size_t)r0t * K + sswz;
  const unsigned short* sB = B + (size_t)r0t * K + sswz;
  const size_t row64 = (size_t)64 * K;
  const size_t hK = (size_t)128 * K;
  const size_t dst0 = (size_t)wid * 512;  // shorts; lane*16B added by HW

  auto stg = [&](unsigned short* region, const unsigned short* sbase, size_t koff) {
    async16(region + dst0, sbase + koff);
    async16(region + 4096 + dst0, sbase + row64 + koff);
  };

  f32x4 acc[8][4];
#pragma unroll
  for (int m = 0; m < 8; ++m)
#pragma unroll
    for (int n = 0; n < 4; ++n) acc[m][n] = (f32x4){0.f, 0.f, 0.f, 0.f};

  // prologue: tile0 all 4 halves (A,B) + tile1 B halves
  stg(LB + 0 * REG, sB, 0);
  stg(LB + 1 * REG, sB, hK);
  stg(LA + 0 * REG, sA, 0);
  stg(LA + 1 * REG, sA, hK);
  stg(LB + 2 * REG, sB, 64);
  stg(LB + 3 * REG, sB, hK + 64);
  asm volatile("s_waitcnt vmcnt(4)" ::: "memory");
  __builtin_amdgcn_s_barrier();

  bf16x8 afr[4][2], bfr[4][2];

  for (int T = 0; T < nt; T += 2) {
    const size_t k1 = (size_t)(T + 1) * 64;
    const size_t k2 = (size_t)((T + 2 < nt) ? T + 2 : 0) * 64;
    const size_t k3 = (size_t)((T + 3 < nt) ? T + 3 : 0) * 64;

    // ==== P0 (tile T, db0): reads B-lo(4) + A-lo(8); stage A-db1-h0(T+1)
#pragma unroll
    for (int nf = 0; nf < 2; ++nf) {
      bfr[nf][0] = *(const bf16x8*)&LB[rB0 + bRow + nf * 1024 + sc0];
      bfr[nf][1] = *(const bf16x8*)&LB[rB0 + bRow + nf * 1024 + sc1];
    }
#pragma unroll
    for (int i = 0; i < 4; ++i) {
      afr[i][0] = *(const bf16x8*)&LA[rA0 + aRow + i * 1024 + sc0];
      afr[i][1] = *(const bf16x8*)&LA[rA0 + aRow + i * 1024 + sc1];
    }
    stg(LA + 2 * REG, sA, k1);
    asm volatile("s_waitcnt lgkmcnt(8)" ::: "memory");
    __builtin_amdgcn_s_barrier();
    asm volatile("s_waitcnt lgkmcnt(0)" ::: "memory");
    __builtin_amdgcn_s_setprio(1);
#pragma unroll
    for (int i = 0; i < 4; ++i)
#pragma unroll
      for (int nf = 0; nf < 2; ++nf)
#pragma unroll
        for (int s = 0; s < 2; ++s)
          acc[i][nf] = __builtin_amdgcn_mfma_f32_16x16x32_bf16(afr[i][s], bfr[nf][s], acc[i][nf], 0, 0, 0);
    __builtin_amdgcn_s_setprio(0);
    __builtin_amdgcn_s_barrier();

    // ==== P1: reads B-hi(4); stage A-db1-h1(T+1)
#pragma unroll
    for (int nf = 2; nf < 4; ++nf) {
      bfr[nf][0] = *(const bf16x8*)&LB[rB0 + bRow + nf * 1024 + sc0];
      bfr[nf][1] = *(const bf16x8*)&LB[rB0 + bRow + nf * 1024 + sc1];
    }
    stg(LA + 3 * REG, sA, hK + k1);
    __builtin_amdgcn_s_barrier();
    asm volatile("s_waitcnt lgkmcnt(0)" ::: "memory");
    __builtin_amdgcn_s_setprio(1);
#pragma unroll
    for (int i = 0; i < 4; ++i)
#pragma unroll
      for (int nf = 2; nf < 4; ++nf)
#pragma unroll
        for (int s = 0; s < 2; ++s)
          acc[i][nf] = __builtin_amdgcn_mfma_f32_16x16x32_bf16(afr[i][s], bfr[nf][s], acc[i][nf], 0, 0, 0);
    __builtin_amdgcn_s_setprio(0);
    __builtin_amdgcn_s_barrier();

    // ==== P2: reads A-hi(8); stage B-db0-h0(T+2)
#pragma unroll
    for (int i = 0; i < 4; ++i) {
      afr[i][0] = *(const bf16x8*)&LA[rA0 + aRow + (4 + i) * 1024 + sc0];
      afr[i][1] = *(const bf16x8*)&LA[rA0 + aRow + (4 + i) * 1024 + sc1];
    }
    stg(LB + 0 * REG, sB, k2);
    __builtin_amdgcn_s_barrier();
    asm volatile("s_waitcnt lgkmcnt(0)" ::: "memory");
    __builtin_amdgcn_s_setprio(1);
#pragma unroll
    for (int i = 0; i < 4; ++i)
#pragma unroll
      for (int nf = 2; nf < 4; ++nf)
#pragma unroll
        for (int s = 0; s < 2; ++s)
          acc[4 + i][nf] = __builtin_amdgcn_mfma_f32_16x16x32_bf16(afr[i][s], bfr[nf][s], acc[4 + i][nf], 0, 0, 0);
    __builtin_amdgcn_s_setprio(0);
    __builtin_amdgcn_s_barrier();

    // ==== P3: no reads (B-lo regs live); stage B-db0-h1(T+2); vmcnt(4)
    stg(LB + 1 * REG, sB, hK + k2);
    asm volatile("s_waitcnt vmcnt(4)" ::: "memory");
    __builtin_amdgcn_s_barrier();
    __builtin_amdgcn_s_setprio(1);
#pragma unroll
    for (int i = 0; i < 4; ++i)
#pragma unroll
      for (int nf = 0; nf < 2; ++nf)
#pragma unroll
        for (int s = 0; s < 2; ++s)
          acc[4 + i][nf] = __builtin_amdgcn_mfma_f32_16x16x32_bf16(afr[i][s], bfr[nf][s], acc[4 + i][nf], 0, 0, 0);
    __builtin_amdgcn_s_setprio(0);
    __builtin_amdgcn_s_barrier();

    // ==== P4 (tile T+1, db1): reads B-lo + A-lo; stage A-db0-h0(T+2)
#pragma unroll
    for (int nf = 0; nf < 2; ++nf) {
      bfr[nf][0] = *(const bf16x8*)&LB[rB1 + bRow + nf * 1024 + sc0];
      bfr[nf][1] = *(const bf16x8*)&LB[rB1 + bRow + nf * 1024 + sc1];
    }
#pragma unroll
    for (int i = 0; i < 4; ++i) {
      afr[i][0] = *(const bf16x8*)&LA[rA1 + aRow + i * 1024 + sc0];
      afr[i][1] = *(const bf16x8*)&LA[rA1 + aRow + i * 1024 + sc1];
    }
    stg(LA + 0 * REG, sA, k2);
    asm volatile("s_waitcnt lgkmcnt(8)" ::: "memory");
    __builtin_amdgcn_s_barrier();
    asm volatile("s_waitcnt lgkmcnt(0)" ::: "memory");
    __builtin_amdgcn_s_setprio(1);
#pragma unroll
    for (int i = 0; i < 4; ++i)
#pragma unroll
      for (int nf = 0; nf < 2; ++nf)
#pragma unroll
        for (int s = 0; s < 2; ++s)
          acc[i][nf] = __builtin_amdgcn_mfma_f32_16x16x32_bf16(afr[i][s], bfr[nf][s], acc[i][nf], 0, 0, 0);
    __builtin_amdgcn_s_setprio(0);
    __builtin_amdgcn_s_barrier();

    // ==== P5: reads B-hi; stage A-db0-h1(T+2)
#pragma unroll
    for (int nf = 2; nf < 4; ++nf) {
      bfr[nf][0] = *(const bf16x8*)&LB[rB1 + bRow + nf * 1024 + sc0];
      bfr[nf][1] = *(const bf16x8*)&LB[rB1 + bRow + nf * 1024 + sc1];
    }
    stg(LA + 1 * REG, sA, hK + k2);
    __builtin_amdgcn_s_barrier();
    asm volatile("s_waitcnt lgkmcnt(0)" ::: "memory");
    __builtin_amdgcn_s_setprio(1);
#pragma unroll
    for (int i = 0; i < 4; ++i)
#pragma unroll
      for (int nf = 2; nf < 4; ++nf)
#pragma unroll
        for (int s = 0; s < 2; ++s)
          acc[i][nf] = __builtin_amdgcn_mfma_f32_16x16x32_bf16(afr[i][s], bfr[nf][s], acc[i][nf], 0, 0, 0);
    __builtin_amdgcn_s_setprio(0);
    __builtin_amdgcn_s_barrier();

    // ==== P6: reads A-hi; stage B-db1-h0(T+3)
#pragma unroll
    for (int i = 0; i < 4; ++i) {
      afr[i][0] = *(const bf16x8*)&LA[rA1 + aRow + (4 + i) * 1024 + sc0];
      afr[i][1] = *(const bf16x8*)&LA[rA1 + aRow + (4 + i) * 1024 + sc1];
    }
    stg(LB + 2 * REG, sB, k3);
    __builtin_amdgcn_s_barrier();
    asm volatile("s_waitcnt lgkmcnt(0)" ::: "memory");
    __builtin_amdgcn_s_setprio(1);
#pragma unroll
    for (int i = 0; i < 4; ++i)
#pragma unroll
      for (int nf = 2; nf < 4; ++nf)
#pragma unroll
        for (int s = 0; s < 2; ++s)
          acc[4 + i][nf] = __builtin_amdgcn_mfma_f32_16x16x32_bf16(afr[i][s], bfr[nf][s], acc[4 + i][nf], 0, 0, 0);
    __builtin_amdgcn_s_setprio(0);
    __builtin_amdgcn_s_barrier();

    // ==== P7: no reads; stage B-db1-h1(T+3); vmcnt(4)
    stg(LB + 3 * REG, sB, hK + k3);
    asm volatile("s_waitcnt vmcnt(4)" ::: "memory");
    __builtin_amdgcn_s_barrier();
    __builtin_amdgcn_s_setprio(1);
#pragma unroll
    for (int i = 0; i < 4; ++i)
#pragma unroll
      for (int nf = 0; nf < 2; ++nf)
#pragma unroll
        for (int s = 0; s < 2; ++s)
          acc[4 + i][nf] = __builtin_amdgcn_mfma_f32_16x16x32_bf16(afr[i][s], bfr[nf][s], acc[4 + i][nf], 0, 0, 0);
    __builtin_amdgcn_s_setprio(0);
    __builtin_amdgcn_s_barrier();
  }
  asm volatile("s_waitcnt vmcnt(0)" ::: "memory");

  // epilogue: n innermost -> each 128B line completed back-to-back (no RMW).
  const int rl = (lane >> 4) * 4;
  const int cl = lane & 15;
  float bv[4];
#pragma unroll
  for (int n = 0; n < 4; ++n) {
    const int col = tn * 256 + wn * 64 + n * 16 + cl;
    bv[n] = bp ? bp[(size_t)e * Nn + col] : 0.f;
  }
#pragma unroll
  for (int m = 0; m < 8; ++m) {
    const int row = row0 + wm * 128 + m * 16 + rl;
#pragma unroll
    for (int jj = 0; jj < 4; ++jj) {
      CT* rowp = Cw + (size_t)(row + jj) * Nn + tn * 256 + wn * 64 + cl;
#pragma unroll
      for (int n = 0; n < 4; ++n) {
        float v = acc[m][n][jj] + bv[n];
        if (GELU) v = 0.5f * v * (1.f + erff(v * 0.70710678118654752f));
        if constexpr (sizeof(CT) == 2) { rowp[n * 16] = (CT)f2bf(v); } else { rowp[n * 16] = (CT)v; }
      }
    }
  }
}

// ---------------- combine: out[t] = g0*(Ya+Yb)[s0] + g1*(Ya+Yb)[s1] ----------------
__global__ __launch_bounds__(256) void combine_kernel(
    const float* __restrict__ Ya, const float* __restrict__ Yb,
    const int* __restrict__ tok_slot, const float* __restrict__ tok_g,
    float* __restrict__ out) {
  const int t = blockIdx.x;
  const int i = threadIdx.x;
  const int s0 = tok_slot[2 * t], s1 = tok_slot[2 * t + 1];
  const float g0 = tok_g[2 * t], g1 = tok_g[2 * t + 1];
  const float4 a0 = ((const float4*)Ya)[(size_t)s0 * 256 + i];
  const float4 b0 = ((const float4*)Yb)[(size_t)s0 * 256 + i];
  const float4 a1 = ((const float4*)Ya)[(size_t)s1 * 256 + i];
  const float4 b1 = ((const float4*)Yb)[(size_t)s1 * 256 + i];
  float4 r;
  r.x = g0 * (a0.x + b0.x) + g1 * (a1.x + b1.x);
  r.y = g0 * (a0.y + b0.y) + g1 * (a1.y + b1.y);
  r.z = g0 * (a0.z + b0.z) + g1 * (a1.z + b1.z);
  r.w = g0 * (a0.w + b0.w) + g1 * (a1.w + b1.w);
  ((float4*)out)[(size_t)t * 256 + i] = r;
}

extern "C" void kernel_launch(void* const* d_in, const int* in_sizes, int n_in,
                              void* d_out, int out_size, void* d_ws, size_t ws_size,
                              hipStream_t stream) {
  const float* x = (const float*)d_in[0];
  const float* Wr = (const float*)d_in[1];
  const float* W1 = (const float*)d_in[2];
  const float* b1 = (const float*)d_in[3];
  const float* W2 = (const float*)d_in[4];
  const float* b2 = (const float*)d_in[5];
  float* out = (float*)d_out;

  char* w = (char*)d_ws;
  size_t ob = 0;
  auto take = [&](size_t nbytes) -> void* {
    void* p = w + ob;
    ob = (ob + nbytes + 255) & ~(size_t)255;
    return p;
  };
  // Overlap: {W1T,Xg} (dead after GEMM1) share a region with {Ya,Yb}
  unsigned short* W2T = (unsigned short*)take((size_t)NE * DM * DFF * 2);   // 64MB
  unsigned short* H = (unsigned short*)take((size_t)CAP * DFF * 2);         // 151MB
  char* R = (char*)take(2 * (size_t)CAP * DM * 4);                          // 151MB
  unsigned short* W1T = (unsigned short*)R;                                 // 64MB
  unsigned short* Xg = (unsigned short*)(R + (size_t)NE * DFF * DM * 2);    // 37.75MB
  float* Ya = (float*)R;                                                    // 75.5MB
  float* Yb = (float*)(R + (size_t)CAP * DM * 4);                           // 75.5MB
  unsigned* counts = (unsigned*)take(NE * 4);
  float* Psum = (float*)take(NE * 4);
  int* offs = (int*)take(16 * 4);
  int* tok_e = (int*)take(2 * N_TOK * 4);
  float* tok_g = (float*)take(2 * N_TOK * 4);
  int* tok_ls = (int*)take(2 * N_TOK * 4);
  int* tok_slot = (int*)take(2 * N_TOK * 4);
  (void)ws_size; (void)in_sizes; (void)n_in; (void)out_size;

  hipFuncSetAttribute(reinterpret_cast<const void*>(&gemm8<1, true, unsigned short>),
                      hipFuncAttributeMaxDynamicSharedMemorySize, 131072);
  hipFuncSetAttribute(reinterpret_cast<const void*>(&gemm8<2, false, float>),
                      hipFuncAttributeMaxDynamicSharedMemorySize, 131072);

  init_kernel<<<1, 64, 0, stream>>>(counts, Psum);
  router_kernel<<<N_TOK / 16, 256, 0, stream>>>(x, Wr, counts, Psum, tok_e, tok_g, tok_ls);
  transpose_cvt<<<dim3(DFF / 64, DM / 64, NE), 256, 0, stream>>>(W1, W1T, DM, DFF);
  transpose_cvt<<<dim3(DM / 64, DFF / 64, NE), 256, 0, stream>>>(W2, W2T, DFF, DM);
  offsets_kernel<<<1, 64, 0, stream>>>(counts, Psum, offs, out + (size_t)N_TOK * DM);
  gather_kernel<<<N_TOK, 256, 0, stream>>>(x, tok_e, tok_ls, offs, tok_slot, Xg);
  // GEMM1: H = gelu(Xg @ W1 + b1); grid: x=tn (A-panel shared), y=global row-tile
  gemm8<1, true, unsigned short><<<dim3(DFF / 256, TMG, 1), 512, 131072, stream>>>(
      Xg, W1T, b1, H, offs, DM, DFF, 0);
  // GEMM2 split-K=2: z = half; halves write Ya / Yb
  gemm8<2, false, float><<<dim3(DM / 256, TMG, 2), 512, 131072, stream>>>(
      H, W2T, b2, Ya, offs, DFF, DM, (size_t)CAP * DM);
  combine_kernel<<<N_TOK, 256, 0, stream>>>(Ya, Yb, tok_slot, tok_g, out);
}